// Round 5
// baseline (561.395 us; speedup 1.0000x reference)
//
#include <hip/hip_runtime.h>

// AssociationLayer: masked Sinkhorn (100 iters) + mutual-argmax assignment.
// R10 (resubmit after infra failure; no counter evidence to act on).
// Both K panels in REGISTERS with the VGPR cap lifted.
//  R9 post-mortem: VGPR_Count pinned at 128 (launch_bounds(512,2) cap) with
//  ~135-reg demand -> residual ~2dword/lane/iter spill (+85 MB writes);
//  KT-in-LDS streams 128 KB/iter (~1000 LDS cyc/CU/iter) + 8-way bank
//  conflicts (1.39e7; KTP=264 -> stride=132 dwords = 4 mod 32).
//  Fix: grid=256=#CUs means 1 block/CU ALWAYS (occupancy is grid-bound, not
//  reg-bound): launch_bounds(512,1) lets the allocator use up to 256 regs
//  (2 waves/SIMD guaranteed by the bound); KA(64)+KB(64)+transients(~60)
//  fits -> zero spill, zero dir2 LDS traffic, zero bank conflicts.
//  - dir1 (K@v): acc = sum_t mfma(KA, VF_broadcast); dir2 (K^T@u):
//    q = sum_t mfma(UF_broadcast, KB). Per-iter LDS = broadcasts + publishes.
//  - epilogue: R7 direct form, interior stores packed 16B/lane (KA lanes own
//    8 consecutive cols -> 2x f4 groups per t), boundary group scalar.
//  - identical (u*k)*v mul order on both panels -> bitwise-consistent
//    mutual-argmax equality tests. absmax ~1.0 (tie flips) vs thr 4.92.

#define T_MAX   256
#define L_FLAT  (257 * 257)
#define N_ITERS 100
#define LAMBDA_F 10.0f
#define EPS_F    1e-12f

#define ROR1 0x121
#define ROR2 0x122
#define ROR4 0x124
#define ROR8 0x128

typedef short bf8   __attribute__((ext_vector_type(8)));  // 8 bf16 = 4 VGPRs
typedef float f32x4 __attribute__((ext_vector_type(4)));

struct F4 { float a, b, c, d; };   // 16B payload, 4B-aligned packed store

template<int CTRL>
__device__ __forceinline__ float dpp_addf(float x) {
    int t = __builtin_amdgcn_update_dpp(0, __float_as_int(x), CTRL, 0xF, 0xF, true);
    return x + __int_as_float(t);
}
__device__ __forceinline__ float swz16_addf(float x) {
    return x + __int_as_float(__builtin_amdgcn_ds_swizzle(__float_as_int(x), 0x401F));
}
__device__ __forceinline__ float swz16_maxf(float x) {
    return fmaxf(x, __int_as_float(__builtin_amdgcn_ds_swizzle(__float_as_int(x), 0x401F)));
}
__device__ __forceinline__ int swz16_ori(int x) {
    return x | __builtin_amdgcn_ds_swizzle(x, 0x401F);
}
__device__ __forceinline__ float fast_rcp(float x) {
#if __has_builtin(__builtin_amdgcn_rcpf)
    return __builtin_amdgcn_rcpf(x);
#else
    return 1.0f / x;
#endif
}
__device__ __forceinline__ unsigned short f2bf(float x) {   // RNE f32->bf16
    unsigned u = __float_as_uint(x);
    return (unsigned short)((u + 0x7FFFu + ((u >> 16) & 1u)) >> 16);
}
__device__ __forceinline__ float bf2f(short s) {            // exact bf16->f32
    return __uint_as_float(((unsigned)(unsigned short)s) << 16);
}

__global__ __launch_bounds__(512, 1) void assoc_sinkhorn_kernel(
    const float* __restrict__ aff,
    const int*   __restrict__ ndet,
    const int*   __restrict__ ntrk,
    float*       __restrict__ out_t,
    float*       __restrict__ out_a)
{
    const int b   = blockIdx.x;
    const int nd  = ndet[b];
    const int nt  = ntrk[b];
    const int tid = threadIdx.x;
    const int w   = tid >> 6;     // wave 0..7
    const int l   = tid & 63;
    const int lr  = l & 15;       // m/n index within 16x16 tile
    const int lk  = l >> 4;       // k-group 0..3

    __shared__ __align__(16) unsigned short u_bf[256];
    __shared__ __align__(16) unsigned short v_bf[256];
    __shared__ __align__(16) float u_f[256];
    __shared__ __align__(16) float v_f[256];
    __shared__ __align__(16) float supart[8];
    __shared__ __align__(16) float svpart[8];
    __shared__ __align__(16) float rm_s[256];
    __shared__ __align__(16) float cm_s[256];

    const float ndf = (float)nd;
    const float ntf = (float)nt;

    // ---------------- prologue: build bf16 K fragments ----------------
    bf8 KA[2][8];   // row-panel (A-operand layout): rows 32w+16a+lr, cols 32t+8lk+j
    bf8 KB[2][8];   // col-panel (B-operand layout): cols 32w+16c+lr, rows 32t+8lk+j
    const float* Ab = aff + (size_t)b * (T_MAX * T_MAX);

    #pragma unroll
    for (int a = 0; a < 2; ++a) {
        const int row = 32 * w + 16 * a + lr;
        const bool rv = (row < nt);
        const float* rp = Ab + (size_t)row * T_MAX;
        #pragma unroll
        for (int t = 0; t < 8; ++t) {
            const int c0 = 32 * t + 8 * lk;
            const float4 x0 = *reinterpret_cast<const float4*>(rp + c0);
            const float4 x1 = *reinterpret_cast<const float4*>(rp + c0 + 4);
            const float e[8] = {x0.x, x0.y, x0.z, x0.w, x1.x, x1.y, x1.z, x1.w};
            bf8 kk;
            #pragma unroll
            for (int j = 0; j < 8; ++j) {
                const float val = (rv && (c0 + j) < nd) ? __expf(LAMBDA_F * e[j]) : 0.0f;
                kk[j] = (short)f2bf(val);
            }
            KA[a][t] = kk;
        }
    }
    #pragma unroll
    for (int c = 0; c < 2; ++c) {
        const int col = 32 * w + 16 * c + lr;
        const bool cv = (col < nd);
        #pragma unroll
        for (int t = 0; t < 8; ++t) {
            const int r0 = 32 * t + 8 * lk;
            bf8 kk;
            #pragma unroll
            for (int j = 0; j < 8; ++j) {
                const float x = Ab[(size_t)(r0 + j) * T_MAX + col];
                const float val = (cv && (r0 + j) < nt) ? __expf(LAMBDA_F * x) : 0.0f;
                kk[j] = (short)f2bf(val);
            }
            KB[c][t] = kk;
        }
    }

    if (tid < 256) {
        v_bf[tid] = (tid < nd) ? f2bf(1.0f) : (unsigned short)0;
        v_f[tid]  = (tid < nd) ? 1.0f : 0.0f;
    }
    __syncthreads();

    float Sv  = ndf;    // sum of v over valid cols (wave-uniform)
    float vbd = 1.0f;   // v[nd]
    float ubd = 0.0f;   // u[nt]

    const int r_a0 = 32 * w + 4 * lk;   // base row of acc0 quad (a=0)
    const int myc0 = 32 * w + lr;       // dir2 col (c=0)
    const int myc1 = myc0 + 16;         // dir2 col (c=1)

    // ---------------- Sinkhorn iterations ----------------
    for (int it = 0; it < N_ITERS; ++it) {
        // ---- dir1: p = K @ v  (row-panel regs, fully in-wave) ----
        bf8 VF[8];
        #pragma unroll
        for (int t = 0; t < 8; ++t)
            VF[t] = *reinterpret_cast<const bf8*>(&v_bf[32 * t + 8 * lk]);

        f32x4 acc0 = {0.0f, 0.0f, 0.0f, 0.0f};
        f32x4 acc1 = {0.0f, 0.0f, 0.0f, 0.0f};
        #pragma unroll
        for (int t = 0; t < 8; ++t) {
            acc0 = __builtin_amdgcn_mfma_f32_16x16x32_bf16(KA[0][t], VF[t], acc0, 0, 0, 0);
            acc1 = __builtin_amdgcn_mfma_f32_16x16x32_bf16(KA[1][t], VF[t], acc1, 0, 0, 0);
        }

        const float ubd_new = ndf * fast_rcp(Sv + vbd + EPS_F);
        const float vbdE = vbd + EPS_F;
        float u8[8];
        #pragma unroll
        for (int q = 0; q < 4; ++q) {
            u8[q]     = ((r_a0 + q)      < nt) ? fast_rcp(acc0[q] + vbdE) : 0.0f;
            u8[4 + q] = ((r_a0 + 16 + q) < nt) ? fast_rcp(acc1[q] + vbdE) : 0.0f;
        }

        // per-wave Sigma(u): values vary over lk only (redundant over lr)
        {
            float su = ((u8[0] + u8[1]) + (u8[2] + u8[3]))
                     + ((u8[4] + u8[5]) + (u8[6] + u8[7]));
            su = swz16_addf(su);
            su += __shfl_xor(su, 32, 64);
            if (l == 0) supart[w] = su;
        }

        // publish u (bf16 for MFMA, f32 for epilogue); writers: lr==0
        if (lr == 0) {
            const unsigned p01 = (unsigned)f2bf(u8[0]) | ((unsigned)f2bf(u8[1]) << 16);
            const unsigned p23 = (unsigned)f2bf(u8[2]) | ((unsigned)f2bf(u8[3]) << 16);
            const unsigned p45 = (unsigned)f2bf(u8[4]) | ((unsigned)f2bf(u8[5]) << 16);
            const unsigned p67 = (unsigned)f2bf(u8[6]) | ((unsigned)f2bf(u8[7]) << 16);
            *reinterpret_cast<uint2*>(&u_bf[r_a0])      = uint2{p01, p23};
            *reinterpret_cast<uint2*>(&u_bf[r_a0 + 16]) = uint2{p45, p67};
            f32x4 uf0 = {u8[0], u8[1], u8[2], u8[3]};
            f32x4 uf1 = {u8[4], u8[5], u8[6], u8[7]};
            *reinterpret_cast<f32x4*>(&u_f[r_a0])      = uf0;
            *reinterpret_cast<f32x4*>(&u_f[r_a0 + 16]) = uf1;
        }
        __syncthreads();   // barrier A: u published

        // ---- dir2: q = K^T @ u  (col-panel regs, fully in-wave) ----
        f32x4 qa0 = {0.0f, 0.0f, 0.0f, 0.0f};
        f32x4 qa1 = {0.0f, 0.0f, 0.0f, 0.0f};
        #pragma unroll
        for (int t = 0; t < 8; ++t) {
            const bf8 UF = *reinterpret_cast<const bf8*>(&u_bf[32 * t + 8 * lk]);
            qa0 = __builtin_amdgcn_mfma_f32_16x16x32_bf16(UF, KB[0][t], qa0, 0, 0, 0);
            qa1 = __builtin_amdgcn_mfma_f32_16x16x32_bf16(UF, KB[1][t], qa1, 0, 0, 0);
        }

        // Su and vbd update (redundant per wave; supart covered by barrier A)
        const f32x4 sp0 = *reinterpret_cast<const f32x4*>(&supart[0]);
        const f32x4 sp1 = *reinterpret_cast<const f32x4*>(&supart[4]);
        const float Su = ((sp0[0] + sp0[1]) + (sp0[2] + sp0[3]))
                       + ((sp1[0] + sp1[1]) + (sp1[2] + sp1[3]));
        const float vbd_new = ntf * fast_rcp(Su + ubd_new + EPS_F);

        const float ubdE = ubd_new + EPS_F;
        const float v0 = (myc0 < nd) ? fast_rcp(qa0[0] + ubdE) : 0.0f;
        const float v1 = (myc1 < nd) ? fast_rcp(qa1[0] + ubdE) : 0.0f;

        // per-wave Sigma(v): values vary over lr only -> all-DPP row reduce
        {
            float sv = v0 + v1;
            sv = dpp_addf<ROR1>(sv);
            sv = dpp_addf<ROR2>(sv);
            sv = dpp_addf<ROR4>(sv);
            sv = dpp_addf<ROR8>(sv);
            if (l == 0) svpart[w] = sv;
        }
        if (lk == 0) {
            v_bf[myc0] = f2bf(v0);
            v_bf[myc1] = f2bf(v1);
            v_f[myc0]  = v0;
            v_f[myc1]  = v1;
        }
        ubd = ubd_new;
        vbd = vbd_new;
        __syncthreads();   // barrier B: v published

        const f32x4 vp0 = *reinterpret_cast<const f32x4*>(&svpart[0]);
        const f32x4 vp1 = *reinterpret_cast<const f32x4*>(&svpart[4]);
        Sv = ((vp0[0] + vp0[1]) + (vp0[2] + vp0[3]))
           + ((vp1[0] + vp1[1]) + (vp1[2] + vp1[3]));
    }

    // ================= epilogue =================
    // rowmax on row-panel, colmax on col-panel; T = (u*k)*v identical order.
    float rm[2];
    #pragma unroll
    for (int a = 0; a < 2; ++a) {
        const int row = 32 * w + 16 * a + lr;
        const float ur = u_f[row];
        float mm = 0.0f;
        #pragma unroll
        for (int t = 0; t < 8; ++t) {
            const f32x4 va = *reinterpret_cast<const f32x4*>(&v_f[32 * t + 8 * lk]);
            const f32x4 vb = *reinterpret_cast<const f32x4*>(&v_f[32 * t + 8 * lk + 4]);
            const float vj[8] = {va[0], va[1], va[2], va[3], vb[0], vb[1], vb[2], vb[3]};
            #pragma unroll
            for (int j = 0; j < 8; ++j) {
                const float tv = ur * bf2f(KA[a][t][j]) * vj[j];
                mm = fmaxf(mm, tv);
            }
        }
        mm = swz16_maxf(mm);
        mm = fmaxf(mm, __shfl_xor(mm, 32, 64));
        rm[a] = mm;
        if (lk == 0) rm_s[row] = mm;
    }
    float cmv[2];
    #pragma unroll
    for (int c = 0; c < 2; ++c) {
        const int col = (c == 0) ? myc0 : myc1;
        const float vc = v_f[col];
        float mm = 0.0f;
        #pragma unroll
        for (int t = 0; t < 8; ++t) {
            const int rb = 32 * t + 8 * lk;
            const f32x4 ua = *reinterpret_cast<const f32x4*>(&u_f[rb]);
            const f32x4 ub = *reinterpret_cast<const f32x4*>(&u_f[rb + 4]);
            const float uj[8] = {ua[0], ua[1], ua[2], ua[3], ub[0], ub[1], ub[2], ub[3]};
            #pragma unroll
            for (int j = 0; j < 8; ++j) {
                const float kv = (c == 0) ? bf2f(KB[0][t][j]) : bf2f(KB[1][t][j]);
                const float tv = uj[j] * kv * vc;
                mm = fmaxf(mm, tv);
            }
        }
        mm = swz16_maxf(mm);
        mm = fmaxf(mm, __shfl_xor(mm, 32, 64));
        cmv[c] = mm;
        if (lk == 0) cm_s[col] = mm;
    }
    __syncthreads();   // rm_s / cm_s published

    float* Ot = out_t + (size_t)b * L_FLAT;
    float* Oa = out_a + (size_t)b * L_FLAT;
    const int stride = nd + 1;

    // births row (col-panel) + corner
    #pragma unroll
    for (int c = 0; c < 2; ++c) {
        const int col = (c == 0) ? myc0 : myc1;
        const float vc = v_f[col];
        const float cmc = cmv[c];
        const bool cv = (col < nd);
        int has = 0;
        #pragma unroll
        for (int t = 0; t < 8; ++t) {
            const int rb = 32 * t + 8 * lk;
            const f32x4 ua = *reinterpret_cast<const f32x4*>(&u_f[rb]);
            const f32x4 ub = *reinterpret_cast<const f32x4*>(&u_f[rb + 4]);
            const f32x4 ra = *reinterpret_cast<const f32x4*>(&rm_s[rb]);
            const f32x4 rb4 = *reinterpret_cast<const f32x4*>(&rm_s[rb + 4]);
            const float uj[8] = {ua[0], ua[1], ua[2], ua[3], ub[0], ub[1], ub[2], ub[3]};
            const float rj[8] = {ra[0], ra[1], ra[2], ra[3], rb4[0], rb4[1], rb4[2], rb4[3]};
            #pragma unroll
            for (int j = 0; j < 8; ++j) {
                const int rowj = rb + j;
                const float kv = (c == 0) ? bf2f(KB[0][t][j]) : bf2f(KB[1][t][j]);
                const float tv = uj[j] * kv * vc;
                const bool bit = (rowj < nt) && cv && (tv == rj[j]) && (tv == cmc);
                has |= bit ? 1 : 0;
            }
        }
        has = swz16_ori(has);
        has |= __shfl_xor(has, 32, 64);
        if (lk == 0 && cv) {
            const int kk = nt * stride + col;
            Ot[kk] = ubd * vc;
            Oa[kk] = has ? 0.0f : 1.0f;
        }
    }
    if (tid == 0) {
        const int kk = nt * stride + nd;
        Ot[kk] = ubd * vbd;
        Oa[kk] = 0.0f;
    }

    // interior + deaths (row-panel, 16B-packed stores per 4-col group)
    #pragma unroll
    for (int a = 0; a < 2; ++a) {
        const int row = 32 * w + 16 * a + lr;
        const float ur = u_f[row];
        const float rma = rm[a];
        const bool rv = (row < nt);
        int has = 0;
        #pragma unroll
        for (int t = 0; t < 8; ++t) {
            const int cb = 32 * t + 8 * lk;
            const f32x4 va  = *reinterpret_cast<const f32x4*>(&v_f[cb]);
            const f32x4 vb  = *reinterpret_cast<const f32x4*>(&v_f[cb + 4]);
            const f32x4 ca  = *reinterpret_cast<const f32x4*>(&cm_s[cb]);
            const f32x4 cb4 = *reinterpret_cast<const f32x4*>(&cm_s[cb + 4]);
            float tvs[8];
            float abs_[8];
            #pragma unroll
            for (int j = 0; j < 4; ++j) {
                const float tv = ur * bf2f(KA[a][t][j]) * va[j];
                const bool bit = rv && ((cb + j) < nd) && (tv == rma) && (tv == ca[j]);
                tvs[j] = tv; abs_[j] = bit ? 1.0f : 0.0f;
                has |= bit ? 1 : 0;
            }
            #pragma unroll
            for (int j = 0; j < 4; ++j) {
                const float tv = ur * bf2f(KA[a][t][4 + j]) * vb[j];
                const bool bit = rv && ((cb + 4 + j) < nd) && (tv == rma) && (tv == cb4[j]);
                tvs[4 + j] = tv; abs_[4 + j] = bit ? 1.0f : 0.0f;
                has |= bit ? 1 : 0;
            }
            if (rv) {
                float* OtR = Ot + (size_t)row * stride;
                float* OaR = Oa + (size_t)row * stride;
                #pragma unroll
                for (int g = 0; g < 2; ++g) {
                    const int c0 = cb + 4 * g;
                    if (c0 + 3 < nd) {
                        F4 ot = {tvs[4*g], tvs[4*g+1], tvs[4*g+2], tvs[4*g+3]};
                        F4 oa = {abs_[4*g], abs_[4*g+1], abs_[4*g+2], abs_[4*g+3]};
                        *reinterpret_cast<F4*>(OtR + c0) = ot;
                        *reinterpret_cast<F4*>(OaR + c0) = oa;
                    } else {
                        #pragma unroll
                        for (int j = 0; j < 4; ++j) {
                            if (c0 + j < nd) {
                                OtR[c0 + j] = tvs[4*g + j];
                                OaR[c0 + j] = abs_[4*g + j];
                            }
                        }
                    }
                }
            }
        }
        has = swz16_ori(has);
        has |= __shfl_xor(has, 32, 64);
        if (lk == 0 && rv) {
            const int kk = row * stride + nd;
            Ot[kk] = ur * vbd;
            Oa[kk] = has ? 0.0f : 1.0f;
        }
    }

    // zero-fill padding [length, L_FLAT)
    const int length = (nt + 1) * stride;
    for (int k = length + tid; k < L_FLAT; k += 512) {
        Ot[k] = 0.0f;
        Oa[k] = 0.0f;
    }
}

extern "C" void kernel_launch(void* const* d_in, const int* in_sizes, int n_in,
                              void* d_out, int out_size, void* d_ws, size_t ws_size,
                              hipStream_t stream)
{
    const float* aff  = (const float*)d_in[0];
    const int*   ndet = (const int*)d_in[1];
    const int*   ntrk = (const int*)d_in[2];
    const int    Bn   = in_sizes[1];
    float* out_t = (float*)d_out;
    float* out_a = out_t + (size_t)Bn * L_FLAT;
    assoc_sinkhorn_kernel<<<dim3(Bn), dim3(512), 0, stream>>>(aff, ndet, ntrk, out_t, out_a);
}

// Round 6
// 493.369 us; speedup vs baseline: 1.1379x; 1.1379x over previous
//
#include <hip/hip_runtime.h>

// AssociationLayer: masked Sinkhorn (100 iters) + mutual-argmax assignment.
// R11: 1024 threads / 16 waves; 16 rows + 16 cols per wave; both K panels
// in registers UNDER the 128-reg cap.
//  Evidence trail: VGPR_Count pinned at 128 across R7/R9/R10 regardless of
//  launch_bounds (compiler splits arch/accum at 128 for 512-thread MFMA
//  kernels); 128-reg demand (KA+KB=128 + transients) -> heavy scratch
//  (R10: 471 MB writes). R9's KT-in-LDS avoided spill but streamed
//  128 KB/iter with 8-way conflicts (1.39e7).
//  Fix: halve the per-wave tile. KA[8](32) + KB[8](32) = 64 persistent regs,
//  peak demand ~105 < 128 -> no spill, no KT, no conflicts; 4 waves/SIMD
//  doubles latency hiding. Loop LDS = u/v bf16 broadcasts only (same-address
//  per 16 lanes -> free). u_f/v_f f32 published once post-loop.
//  - dir1 (K@v): acc = sum_t mfma(KA[t], VF[t]); u rows 16w+4lk+q
//  - dir2 (K^T@u): qa = sum_t mfma(UF[t], KB[t]); v col 16w+lr (qa[0])
//  - epilogue: identical (u*k)*v mul order on both panels -> bitwise-
//    consistent mutual-argmax; interior stores packed 16B/lane.
//  absmax ~1.0 (argmax tie flips from bf16 K) vs threshold 4.92.

#define T_MAX   256
#define L_FLAT  (257 * 257)
#define N_ITERS 100
#define LAMBDA_F 10.0f
#define EPS_F    1e-12f

#define ROR1 0x121
#define ROR2 0x122
#define ROR4 0x124
#define ROR8 0x128

typedef short bf8   __attribute__((ext_vector_type(8)));  // 8 bf16 = 4 VGPRs
typedef float f32x4 __attribute__((ext_vector_type(4)));

struct F4 { float a, b, c, d; };   // 16B payload, 4B-aligned packed store

template<int CTRL>
__device__ __forceinline__ float dpp_addf(float x) {
    int t = __builtin_amdgcn_update_dpp(0, __float_as_int(x), CTRL, 0xF, 0xF, true);
    return x + __int_as_float(t);
}
__device__ __forceinline__ float swz16_addf(float x) {
    return x + __int_as_float(__builtin_amdgcn_ds_swizzle(__float_as_int(x), 0x401F));
}
__device__ __forceinline__ float swz16_maxf(float x) {
    return fmaxf(x, __int_as_float(__builtin_amdgcn_ds_swizzle(__float_as_int(x), 0x401F)));
}
__device__ __forceinline__ int swz16_ori(int x) {
    return x | __builtin_amdgcn_ds_swizzle(x, 0x401F);
}
__device__ __forceinline__ float fast_rcp(float x) {
#if __has_builtin(__builtin_amdgcn_rcpf)
    return __builtin_amdgcn_rcpf(x);
#else
    return 1.0f / x;
#endif
}
__device__ __forceinline__ unsigned short f2bf(float x) {   // RNE f32->bf16
    unsigned u = __float_as_uint(x);
    return (unsigned short)((u + 0x7FFFu + ((u >> 16) & 1u)) >> 16);
}
__device__ __forceinline__ float bf2f(short s) {            // exact bf16->f32
    return __uint_as_float(((unsigned)(unsigned short)s) << 16);
}

__global__ __launch_bounds__(1024, 1) void assoc_sinkhorn_kernel(
    const float* __restrict__ aff,
    const int*   __restrict__ ndet,
    const int*   __restrict__ ntrk,
    float*       __restrict__ out_t,
    float*       __restrict__ out_a)
{
    const int b   = blockIdx.x;
    const int nd  = ndet[b];
    const int nt  = ntrk[b];
    const int tid = threadIdx.x;
    const int w   = tid >> 6;     // wave 0..15 -> rows/cols 16w..16w+15
    const int l   = tid & 63;
    const int lr  = l & 15;       // m/n index within 16x16 tile
    const int lk  = l >> 4;       // k-group 0..3

    __shared__ __align__(16) unsigned short u_bf[256];
    __shared__ __align__(16) unsigned short v_bf[256];
    __shared__ __align__(16) float u_f[256];
    __shared__ __align__(16) float v_f[256];
    __shared__ __align__(16) float supart[16];
    __shared__ __align__(16) float svpart[16];
    __shared__ __align__(16) float rm_s[256];
    __shared__ __align__(16) float cm_s[256];

    const float ndf = (float)nd;
    const float ntf = (float)nt;

    // ---------------- prologue: build bf16 K fragments ----------------
    bf8 KA[8];   // row-panel (A-op): row 16w+lr, cols 32t+8lk+j
    bf8 KB[8];   // col-panel (B-op): col 16w+lr, rows 32t+8lk+j
    const float* Ab = aff + (size_t)b * (T_MAX * T_MAX);

    const int myrow = 16 * w + lr;
    const int mycol = 16 * w + lr;
    {
        const bool rv = (myrow < nt);
        const float* rp = Ab + (size_t)myrow * T_MAX;
        #pragma unroll
        for (int t = 0; t < 8; ++t) {
            const int c0 = 32 * t + 8 * lk;
            const float4 x0 = *reinterpret_cast<const float4*>(rp + c0);
            const float4 x1 = *reinterpret_cast<const float4*>(rp + c0 + 4);
            const float e[8] = {x0.x, x0.y, x0.z, x0.w, x1.x, x1.y, x1.z, x1.w};
            bf8 kk;
            #pragma unroll
            for (int j = 0; j < 8; ++j) {
                const float val = (rv && (c0 + j) < nd) ? __expf(LAMBDA_F * e[j]) : 0.0f;
                kk[j] = (short)f2bf(val);
            }
            KA[t] = kk;
        }
    }
    {
        const bool cv = (mycol < nd);
        #pragma unroll
        for (int t = 0; t < 8; ++t) {
            const int r0 = 32 * t + 8 * lk;
            bf8 kk;
            #pragma unroll
            for (int j = 0; j < 8; ++j) {
                const float x = Ab[(size_t)(r0 + j) * T_MAX + mycol];
                const float val = (cv && (r0 + j) < nt) ? __expf(LAMBDA_F * x) : 0.0f;
                kk[j] = (short)f2bf(val);
            }
            KB[t] = kk;
        }
    }

    if (tid < 256) v_bf[tid] = (tid < nd) ? f2bf(1.0f) : (unsigned short)0;
    __syncthreads();

    float Sv  = ndf;    // sum of v over valid cols (uniform)
    float vbd = 1.0f;   // v[nd]
    float ubd = 0.0f;   // u[nt]

    const int r_a0 = 16 * w + 4 * lk;   // base row of this lane's acc quad
    float u4[4] = {0.f, 0.f, 0.f, 0.f};
    float v0 = 0.0f;

    // ---------------- Sinkhorn iterations ----------------
    for (int it = 0; it < N_ITERS; ++it) {
        // ---- dir1: p = K @ v (regs; VF = broadcast of v over lanes) ----
        f32x4 acc = {0.0f, 0.0f, 0.0f, 0.0f};
        #pragma unroll
        for (int t = 0; t < 8; ++t) {
            const bf8 VF = *reinterpret_cast<const bf8*>(&v_bf[32 * t + 8 * lk]);
            acc = __builtin_amdgcn_mfma_f32_16x16x32_bf16(KA[t], VF, acc, 0, 0, 0);
        }

        const float ubd_new = ndf * fast_rcp(Sv + vbd + EPS_F);
        const float vbdE = vbd + EPS_F;
        #pragma unroll
        for (int q = 0; q < 4; ++q)
            u4[q] = ((r_a0 + q) < nt) ? fast_rcp(acc[q] + vbdE) : 0.0f;

        // wave Sigma(u) over its 16 rows: sum q, reduce over lk (x16, x32)
        {
            float su = (u4[0] + u4[1]) + (u4[2] + u4[3]);
            su = swz16_addf(su);
            su += __shfl_xor(su, 32, 64);
            if (l == 0) supart[w] = su;
        }

        // publish u as bf16; writers: lr==0 lanes (4 rows each)
        if (lr == 0) {
            const unsigned p01 = (unsigned)f2bf(u4[0]) | ((unsigned)f2bf(u4[1]) << 16);
            const unsigned p23 = (unsigned)f2bf(u4[2]) | ((unsigned)f2bf(u4[3]) << 16);
            *reinterpret_cast<uint2*>(&u_bf[r_a0]) = uint2{p01, p23};
        }
        __syncthreads();   // barrier A: u published

        // ---- dir2: q = K^T @ u (regs; UF = broadcast of u) ----
        f32x4 qa = {0.0f, 0.0f, 0.0f, 0.0f};
        #pragma unroll
        for (int t = 0; t < 8; ++t) {
            const bf8 UF = *reinterpret_cast<const bf8*>(&u_bf[32 * t + 8 * lk]);
            qa = __builtin_amdgcn_mfma_f32_16x16x32_bf16(UF, KB[t], qa, 0, 0, 0);
        }

        // Su (16 partials) and border updates (uniform across threads)
        const f32x4 sp0 = *reinterpret_cast<const f32x4*>(&supart[0]);
        const f32x4 sp1 = *reinterpret_cast<const f32x4*>(&supart[4]);
        const f32x4 sp2 = *reinterpret_cast<const f32x4*>(&supart[8]);
        const f32x4 sp3 = *reinterpret_cast<const f32x4*>(&supart[12]);
        const float Su = (((sp0[0]+sp0[1])+(sp0[2]+sp0[3])) + ((sp1[0]+sp1[1])+(sp1[2]+sp1[3])))
                       + (((sp2[0]+sp2[1])+(sp2[2]+sp2[3])) + ((sp3[0]+sp3[1])+(sp3[2]+sp3[3])));
        const float vbd_new = ntf * fast_rcp(Su + ubd_new + EPS_F);

        const float ubdE = ubd_new + EPS_F;
        v0 = (mycol < nd) ? fast_rcp(qa[0] + ubdE) : 0.0f;

        // wave Sigma(v) over its 16 cols: values vary over lr only
        {
            float sv = v0;
            sv = dpp_addf<ROR1>(sv);
            sv = dpp_addf<ROR2>(sv);
            sv = dpp_addf<ROR4>(sv);
            sv = dpp_addf<ROR8>(sv);
            if (l == 0) svpart[w] = sv;
        }
        if (lk == 0) v_bf[mycol] = f2bf(v0);
        ubd = ubd_new;
        vbd = vbd_new;
        __syncthreads();   // barrier B: v published

        const f32x4 vp0 = *reinterpret_cast<const f32x4*>(&svpart[0]);
        const f32x4 vp1 = *reinterpret_cast<const f32x4*>(&svpart[4]);
        const f32x4 vp2 = *reinterpret_cast<const f32x4*>(&svpart[8]);
        const f32x4 vp3 = *reinterpret_cast<const f32x4*>(&svpart[12]);
        Sv = (((vp0[0]+vp0[1])+(vp0[2]+vp0[3])) + ((vp1[0]+vp1[1])+(vp1[2]+vp1[3])))
           + (((vp2[0]+vp2[1])+(vp2[2]+vp2[3])) + ((vp3[0]+vp3[1])+(vp3[2]+vp3[3])));
    }

    // ---- publish final u, v in f32 for the epilogue ----
    if (lr == 0) {
        f32x4 uf = {u4[0], u4[1], u4[2], u4[3]};
        *reinterpret_cast<f32x4*>(&u_f[r_a0]) = uf;
    }
    if (lk == 0) v_f[mycol] = v0;
    __syncthreads();

    // ================= epilogue =================
    // T = (u*k)*v with identical mul order on both panels -> bitwise-
    // consistent equality tests for mutual argmax.
    float rm;   // rowmax of this lane's row
    {
        const float ur = u_f[myrow];
        float mm = 0.0f;
        #pragma unroll
        for (int t = 0; t < 8; ++t) {
            const f32x4 va = *reinterpret_cast<const f32x4*>(&v_f[32 * t + 8 * lk]);
            const f32x4 vb = *reinterpret_cast<const f32x4*>(&v_f[32 * t + 8 * lk + 4]);
            const float vj[8] = {va[0], va[1], va[2], va[3], vb[0], vb[1], vb[2], vb[3]};
            #pragma unroll
            for (int j = 0; j < 8; ++j) {
                const float tv = ur * bf2f(KA[t][j]) * vj[j];
                mm = fmaxf(mm, tv);
            }
        }
        mm = swz16_maxf(mm);
        mm = fmaxf(mm, __shfl_xor(mm, 32, 64));
        rm = mm;
        if (lk == 0) rm_s[myrow] = mm;
    }
    float cmv;  // colmax of this lane's col
    {
        const float vc = v_f[mycol];
        float mm = 0.0f;
        #pragma unroll
        for (int t = 0; t < 8; ++t) {
            const int rb = 32 * t + 8 * lk;
            const f32x4 ua = *reinterpret_cast<const f32x4*>(&u_f[rb]);
            const f32x4 ub = *reinterpret_cast<const f32x4*>(&u_f[rb + 4]);
            const float uj[8] = {ua[0], ua[1], ua[2], ua[3], ub[0], ub[1], ub[2], ub[3]};
            #pragma unroll
            for (int j = 0; j < 8; ++j) {
                const float tv = uj[j] * bf2f(KB[t][j]) * vc;
                mm = fmaxf(mm, tv);
            }
        }
        mm = swz16_maxf(mm);
        mm = fmaxf(mm, __shfl_xor(mm, 32, 64));
        cmv = mm;
        if (lk == 0) cm_s[mycol] = mm;
    }
    __syncthreads();   // rm_s / cm_s published

    float* Ot = out_t + (size_t)b * L_FLAT;
    float* Oa = out_a + (size_t)b * L_FLAT;
    const int stride = nd + 1;

    // births row (col-panel: col-has + write) + corner
    {
        const float vc = v_f[mycol];
        const bool cv = (mycol < nd);
        int has = 0;
        #pragma unroll
        for (int t = 0; t < 8; ++t) {
            const int rb = 32 * t + 8 * lk;
            const f32x4 ua = *reinterpret_cast<const f32x4*>(&u_f[rb]);
            const f32x4 ub = *reinterpret_cast<const f32x4*>(&u_f[rb + 4]);
            const f32x4 ra = *reinterpret_cast<const f32x4*>(&rm_s[rb]);
            const f32x4 rb4 = *reinterpret_cast<const f32x4*>(&rm_s[rb + 4]);
            const float uj[8] = {ua[0], ua[1], ua[2], ua[3], ub[0], ub[1], ub[2], ub[3]};
            const float rj[8] = {ra[0], ra[1], ra[2], ra[3], rb4[0], rb4[1], rb4[2], rb4[3]};
            #pragma unroll
            for (int j = 0; j < 8; ++j) {
                const int rowj = rb + j;
                const float tv = uj[j] * bf2f(KB[t][j]) * vc;
                const bool bit = (rowj < nt) && cv && (tv == rj[j]) && (tv == cmv);
                has |= bit ? 1 : 0;
            }
        }
        has = swz16_ori(has);
        has |= __shfl_xor(has, 32, 64);
        if (lk == 0 && cv) {
            const int kk = nt * stride + mycol;
            Ot[kk] = ubd * vc;
            Oa[kk] = has ? 0.0f : 1.0f;
        }
    }
    if (tid == 0) {
        const int kk = nt * stride + nd;
        Ot[kk] = ubd * vbd;
        Oa[kk] = 0.0f;
    }

    // interior + deaths (row-panel, 16B-packed stores per 4-col group)
    {
        const float ur = u_f[myrow];
        const bool rv = (myrow < nt);
        int has = 0;
        #pragma unroll
        for (int t = 0; t < 8; ++t) {
            const int cb = 32 * t + 8 * lk;
            const f32x4 va  = *reinterpret_cast<const f32x4*>(&v_f[cb]);
            const f32x4 vb  = *reinterpret_cast<const f32x4*>(&v_f[cb + 4]);
            const f32x4 ca  = *reinterpret_cast<const f32x4*>(&cm_s[cb]);
            const f32x4 cb4 = *reinterpret_cast<const f32x4*>(&cm_s[cb + 4]);
            float tvs[8];
            float abs_[8];
            #pragma unroll
            for (int j = 0; j < 4; ++j) {
                const float tv = ur * bf2f(KA[t][j]) * va[j];
                const bool bit = rv && ((cb + j) < nd) && (tv == rm) && (tv == ca[j]);
                tvs[j] = tv; abs_[j] = bit ? 1.0f : 0.0f;
                has |= bit ? 1 : 0;
            }
            #pragma unroll
            for (int j = 0; j < 4; ++j) {
                const float tv = ur * bf2f(KA[t][4 + j]) * vb[j];
                const bool bit = rv && ((cb + 4 + j) < nd) && (tv == rm) && (tv == cb4[j]);
                tvs[4 + j] = tv; abs_[4 + j] = bit ? 1.0f : 0.0f;
                has |= bit ? 1 : 0;
            }
            if (rv) {
                float* OtR = Ot + (size_t)myrow * stride;
                float* OaR = Oa + (size_t)myrow * stride;
                #pragma unroll
                for (int g = 0; g < 2; ++g) {
                    const int c0 = cb + 4 * g;
                    if (c0 + 3 < nd) {
                        F4 ot = {tvs[4*g], tvs[4*g+1], tvs[4*g+2], tvs[4*g+3]};
                        F4 oa = {abs_[4*g], abs_[4*g+1], abs_[4*g+2], abs_[4*g+3]};
                        *reinterpret_cast<F4*>(OtR + c0) = ot;
                        *reinterpret_cast<F4*>(OaR + c0) = oa;
                    } else {
                        #pragma unroll
                        for (int j = 0; j < 4; ++j) {
                            if (c0 + j < nd) {
                                OtR[c0 + j] = tvs[4*g + j];
                                OaR[c0 + j] = abs_[4*g + j];
                            }
                        }
                    }
                }
            }
        }
        has = swz16_ori(has);
        has |= __shfl_xor(has, 32, 64);
        if (lk == 0 && rv) {
            const int kk = myrow * stride + nd;
            Ot[kk] = ur * vbd;
            Oa[kk] = has ? 0.0f : 1.0f;
        }
    }

    // zero-fill padding [length, L_FLAT)
    const int length = (nt + 1) * stride;
    for (int k = length + tid; k < L_FLAT; k += 1024) {
        Ot[k] = 0.0f;
        Oa[k] = 0.0f;
    }
}

extern "C" void kernel_launch(void* const* d_in, const int* in_sizes, int n_in,
                              void* d_out, int out_size, void* d_ws, size_t ws_size,
                              hipStream_t stream)
{
    const float* aff  = (const float*)d_in[0];
    const int*   ndet = (const int*)d_in[1];
    const int*   ntrk = (const int*)d_in[2];
    const int    Bn   = in_sizes[1];
    float* out_t = (float*)d_out;
    float* out_a = out_t + (size_t)Bn * L_FLAT;
    assoc_sinkhorn_kernel<<<dim3(Bn), dim3(1024), 0, stream>>>(aff, ndet, ntrk, out_t, out_a);
}

// Round 7
// 402.585 us; speedup vs baseline: 1.3945x; 1.2255x over previous
//
#include <hip/hip_runtime.h>

// AssociationLayer: masked Sinkhorn (100 iters) + mutual-argmax assignment.
// R12: 1024 threads; KA in regs; K^T in LDS in FRAGMENT-LINEAR layout.
//  Evidence (R7/R10/R11): any attempt to keep the K^T panel in registers
//  spills ~280 MB/dispatch (compiler caps at 128 arch regs / 64V+64A split).
//  R9 (K^T in LDS, no KB regs) was best (283 us) but paid 1.39e7 bank
//  conflicts ([col][row] layout, stride 4 mod 32) and ran 2 waves/SIMD.
//  R12: each lane's dir2 B-fragment is read ONLY by the lane that wrote it
//  -> store K^T as KTL[w][t][lane][8 bf16]: consecutive lanes hit
//  consecutive 16B -> stride-1 ds_read_b128/ds_write_b128, ZERO conflicts.
//  This is a controlled spill-to-LDS replacing the compiler's scratch spill.
//  1024 thr = 4 waves/SIMD latency hiding; per-wave regs ~95 < 128 cap.
//  - dir1 (K@v): acc = sum_t mfma(KA[t], VF[t]); u rows 16w+4lk+q
//  - dir2 (K^T@u): qa = sum_t mfma(UF[t], KTL[w][t][l]); v col 16w+lr
//  - epilogue: identical (u*k)*v mul order on both panels (KA regs /
//    KTL reads) -> bitwise-consistent mutual argmax; 16B packed stores.
//  absmax ~1.0 (argmax tie flips from bf16 K) vs threshold 4.92.

#define T_MAX   256
#define L_FLAT  (257 * 257)
#define N_ITERS 100
#define LAMBDA_F 10.0f
#define EPS_F    1e-12f

#define ROR1 0x121
#define ROR2 0x122
#define ROR4 0x124
#define ROR8 0x128

typedef short bf8   __attribute__((ext_vector_type(8)));  // 8 bf16 = 4 VGPRs
typedef float f32x4 __attribute__((ext_vector_type(4)));

struct F4 { float a, b, c, d; };   // 16B payload, 4B-aligned packed store

template<int CTRL>
__device__ __forceinline__ float dpp_addf(float x) {
    int t = __builtin_amdgcn_update_dpp(0, __float_as_int(x), CTRL, 0xF, 0xF, true);
    return x + __int_as_float(t);
}
__device__ __forceinline__ float swz16_addf(float x) {
    return x + __int_as_float(__builtin_amdgcn_ds_swizzle(__float_as_int(x), 0x401F));
}
__device__ __forceinline__ float swz16_maxf(float x) {
    return fmaxf(x, __int_as_float(__builtin_amdgcn_ds_swizzle(__float_as_int(x), 0x401F)));
}
__device__ __forceinline__ int swz16_ori(int x) {
    return x | __builtin_amdgcn_ds_swizzle(x, 0x401F);
}
__device__ __forceinline__ float fast_rcp(float x) {
#if __has_builtin(__builtin_amdgcn_rcpf)
    return __builtin_amdgcn_rcpf(x);
#else
    return 1.0f / x;
#endif
}
__device__ __forceinline__ unsigned short f2bf(float x) {   // RNE f32->bf16
    unsigned u = __float_as_uint(x);
    return (unsigned short)((u + 0x7FFFu + ((u >> 16) & 1u)) >> 16);
}
__device__ __forceinline__ float bf2f(short s) {            // exact bf16->f32
    return __uint_as_float(((unsigned)(unsigned short)s) << 16);
}

__global__ __launch_bounds__(1024, 1) void assoc_sinkhorn_kernel(
    const float* __restrict__ aff,
    const int*   __restrict__ ndet,
    const int*   __restrict__ ntrk,
    float*       __restrict__ out_t,
    float*       __restrict__ out_a)
{
    const int b   = blockIdx.x;
    const int nd  = ndet[b];
    const int nt  = ntrk[b];
    const int tid = threadIdx.x;
    const int w   = tid >> 6;     // wave 0..15 -> rows/cols 16w..16w+15
    const int l   = tid & 63;
    const int lr  = l & 15;       // m/n index within 16x16 tile
    const int lk  = l >> 4;       // k-group 0..3

    // K^T fragment-linear: [w][t][lane][8 bf16] -> 16B/lane, stride-1 b128
    __shared__ __align__(16) unsigned short KTL[16 * 8 * 64 * 8];   // 128 KB
    __shared__ __align__(16) unsigned short u_bf[256];
    __shared__ __align__(16) unsigned short v_bf[256];
    __shared__ __align__(16) float u_f[256];
    __shared__ __align__(16) float v_f[256];
    __shared__ __align__(16) float supart[16];
    __shared__ __align__(16) float svpart[16];
    __shared__ __align__(16) float rm_s[256];
    __shared__ __align__(16) float cm_s[256];

    const float ndf = (float)nd;
    const float ntf = (float)nt;

    // ---------------- prologue: build bf16 K fragments ----------------
    bf8 KA[8];   // row-panel (A-op): row 16w+lr, cols 32t+8lk+j
    const float* Ab = aff + (size_t)b * (T_MAX * T_MAX);

    const int myrow = 16 * w + lr;
    const int mycol = 16 * w + lr;
    unsigned short* myKTL = &KTL[(size_t)(w * 8 * 64 + l) * 8];   // + t*512

    {
        const bool rv = (myrow < nt);
        const float* rp = Ab + (size_t)myrow * T_MAX;
        #pragma unroll
        for (int t = 0; t < 8; ++t) {
            const int c0 = 32 * t + 8 * lk;
            const float4 x0 = *reinterpret_cast<const float4*>(rp + c0);
            const float4 x1 = *reinterpret_cast<const float4*>(rp + c0 + 4);
            const float e[8] = {x0.x, x0.y, x0.z, x0.w, x1.x, x1.y, x1.z, x1.w};
            bf8 kk;
            #pragma unroll
            for (int j = 0; j < 8; ++j) {
                const float val = (rv && (c0 + j) < nd) ? __expf(LAMBDA_F * e[j]) : 0.0f;
                kk[j] = (short)f2bf(val);
            }
            KA[t] = kk;
        }
    }
    {
        // col-panel (B-op): col 16w+lr, rows 32t+8lk+j -> straight to LDS
        const bool cv = (mycol < nd);
        #pragma unroll
        for (int t = 0; t < 8; ++t) {
            const int r0 = 32 * t + 8 * lk;
            bf8 kk;
            #pragma unroll
            for (int j = 0; j < 8; ++j) {
                const float x = Ab[(size_t)(r0 + j) * T_MAX + mycol];
                const float val = (cv && (r0 + j) < nt) ? __expf(LAMBDA_F * x) : 0.0f;
                kk[j] = (short)f2bf(val);
            }
            *reinterpret_cast<bf8*>(myKTL + t * 512) = kk;   // lane-linear b128
        }
    }

    if (tid < 256) v_bf[tid] = (tid < nd) ? f2bf(1.0f) : (unsigned short)0;
    __syncthreads();

    float Sv  = ndf;    // sum of v over valid cols (uniform)
    float vbd = 1.0f;   // v[nd]
    float ubd = 0.0f;   // u[nt]

    const int r_a0 = 16 * w + 4 * lk;   // base row of this lane's acc quad
    float u4[4] = {0.f, 0.f, 0.f, 0.f};
    float v0 = 0.0f;

    // ---------------- Sinkhorn iterations ----------------
    for (int it = 0; it < N_ITERS; ++it) {
        // ---- dir1: p = K @ v (KA regs; VF = broadcast of v) ----
        f32x4 acc = {0.0f, 0.0f, 0.0f, 0.0f};
        #pragma unroll
        for (int t = 0; t < 8; ++t) {
            const bf8 VF = *reinterpret_cast<const bf8*>(&v_bf[32 * t + 8 * lk]);
            acc = __builtin_amdgcn_mfma_f32_16x16x32_bf16(KA[t], VF, acc, 0, 0, 0);
        }

        const float ubd_new = ndf * fast_rcp(Sv + vbd + EPS_F);
        const float vbdE = vbd + EPS_F;
        #pragma unroll
        for (int q = 0; q < 4; ++q)
            u4[q] = ((r_a0 + q) < nt) ? fast_rcp(acc[q] + vbdE) : 0.0f;

        // wave Sigma(u) over its 16 rows: sum q, reduce over lk (x16, x32)
        {
            float su = (u4[0] + u4[1]) + (u4[2] + u4[3]);
            su = swz16_addf(su);
            su += __shfl_xor(su, 32, 64);
            if (l == 0) supart[w] = su;
        }

        // publish u as bf16; writers: lr==0 lanes (4 rows each)
        if (lr == 0) {
            const unsigned p01 = (unsigned)f2bf(u4[0]) | ((unsigned)f2bf(u4[1]) << 16);
            const unsigned p23 = (unsigned)f2bf(u4[2]) | ((unsigned)f2bf(u4[3]) << 16);
            *reinterpret_cast<uint2*>(&u_bf[r_a0]) = uint2{p01, p23};
        }
        __syncthreads();   // barrier A: u published

        // ---- dir2: q = K^T @ u (B-frags: lane-linear KTL reads) ----
        f32x4 qa = {0.0f, 0.0f, 0.0f, 0.0f};
        #pragma unroll
        for (int t = 0; t < 8; ++t) {
            const bf8 UF = *reinterpret_cast<const bf8*>(&u_bf[32 * t + 8 * lk]);
            const bf8 kb = *reinterpret_cast<const bf8*>(myKTL + t * 512);
            qa = __builtin_amdgcn_mfma_f32_16x16x32_bf16(UF, kb, qa, 0, 0, 0);
        }

        // Su (16 partials) and border updates (uniform across threads)
        const f32x4 sp0 = *reinterpret_cast<const f32x4*>(&supart[0]);
        const f32x4 sp1 = *reinterpret_cast<const f32x4*>(&supart[4]);
        const f32x4 sp2 = *reinterpret_cast<const f32x4*>(&supart[8]);
        const f32x4 sp3 = *reinterpret_cast<const f32x4*>(&supart[12]);
        const float Su = (((sp0[0]+sp0[1])+(sp0[2]+sp0[3])) + ((sp1[0]+sp1[1])+(sp1[2]+sp1[3])))
                       + (((sp2[0]+sp2[1])+(sp2[2]+sp2[3])) + ((sp3[0]+sp3[1])+(sp3[2]+sp3[3])));
        const float vbd_new = ntf * fast_rcp(Su + ubd_new + EPS_F);

        const float ubdE = ubd_new + EPS_F;
        v0 = (mycol < nd) ? fast_rcp(qa[0] + ubdE) : 0.0f;

        // wave Sigma(v) over its 16 cols: values vary over lr only
        {
            float sv = v0;
            sv = dpp_addf<ROR1>(sv);
            sv = dpp_addf<ROR2>(sv);
            sv = dpp_addf<ROR4>(sv);
            sv = dpp_addf<ROR8>(sv);
            if (l == 0) svpart[w] = sv;
        }
        if (lk == 0) v_bf[mycol] = f2bf(v0);
        ubd = ubd_new;
        vbd = vbd_new;
        __syncthreads();   // barrier B: v published

        const f32x4 vp0 = *reinterpret_cast<const f32x4*>(&svpart[0]);
        const f32x4 vp1 = *reinterpret_cast<const f32x4*>(&svpart[4]);
        const f32x4 vp2 = *reinterpret_cast<const f32x4*>(&svpart[8]);
        const f32x4 vp3 = *reinterpret_cast<const f32x4*>(&svpart[12]);
        Sv = (((vp0[0]+vp0[1])+(vp0[2]+vp0[3])) + ((vp1[0]+vp1[1])+(vp1[2]+vp1[3])))
           + (((vp2[0]+vp2[1])+(vp2[2]+vp2[3])) + ((vp3[0]+vp3[1])+(vp3[2]+vp3[3])));
    }

    // ---- publish final u, v in f32 for the epilogue ----
    if (lr == 0) {
        f32x4 uf = {u4[0], u4[1], u4[2], u4[3]};
        *reinterpret_cast<f32x4*>(&u_f[r_a0]) = uf;
    }
    if (lk == 0) v_f[mycol] = v0;
    __syncthreads();

    // ================= epilogue =================
    // T = (u*k)*v with identical mul order on both panels -> bitwise-
    // consistent equality tests for mutual argmax.
    float rm;   // rowmax of this lane's row
    {
        const float ur = u_f[myrow];
        float mm = 0.0f;
        #pragma unroll
        for (int t = 0; t < 8; ++t) {
            const f32x4 va = *reinterpret_cast<const f32x4*>(&v_f[32 * t + 8 * lk]);
            const f32x4 vb = *reinterpret_cast<const f32x4*>(&v_f[32 * t + 8 * lk + 4]);
            const float vj[8] = {va[0], va[1], va[2], va[3], vb[0], vb[1], vb[2], vb[3]};
            #pragma unroll
            for (int j = 0; j < 8; ++j) {
                const float tv = ur * bf2f(KA[t][j]) * vj[j];
                mm = fmaxf(mm, tv);
            }
        }
        mm = swz16_maxf(mm);
        mm = fmaxf(mm, __shfl_xor(mm, 32, 64));
        rm = mm;
        if (lk == 0) rm_s[myrow] = mm;
    }
    float cmv;  // colmax of this lane's col
    {
        const float vc = v_f[mycol];
        float mm = 0.0f;
        #pragma unroll
        for (int t = 0; t < 8; ++t) {
            const int rb = 32 * t + 8 * lk;
            const bf8 kb = *reinterpret_cast<const bf8*>(myKTL + t * 512);
            const f32x4 ua = *reinterpret_cast<const f32x4*>(&u_f[rb]);
            const f32x4 ub = *reinterpret_cast<const f32x4*>(&u_f[rb + 4]);
            const float uj[8] = {ua[0], ua[1], ua[2], ua[3], ub[0], ub[1], ub[2], ub[3]};
            #pragma unroll
            for (int j = 0; j < 8; ++j) {
                const float tv = uj[j] * bf2f(kb[j]) * vc;
                mm = fmaxf(mm, tv);
            }
        }
        mm = swz16_maxf(mm);
        mm = fmaxf(mm, __shfl_xor(mm, 32, 64));
        cmv = mm;
        if (lk == 0) cm_s[mycol] = mm;
    }
    __syncthreads();   // rm_s / cm_s published

    float* Ot = out_t + (size_t)b * L_FLAT;
    float* Oa = out_a + (size_t)b * L_FLAT;
    const int stride = nd + 1;

    // births row (col-panel: col-has + write) + corner
    {
        const float vc = v_f[mycol];
        const bool cv = (mycol < nd);
        int has = 0;
        #pragma unroll
        for (int t = 0; t < 8; ++t) {
            const int rb = 32 * t + 8 * lk;
            const bf8 kb = *reinterpret_cast<const bf8*>(myKTL + t * 512);
            const f32x4 ua = *reinterpret_cast<const f32x4*>(&u_f[rb]);
            const f32x4 ub = *reinterpret_cast<const f32x4*>(&u_f[rb + 4]);
            const f32x4 ra = *reinterpret_cast<const f32x4*>(&rm_s[rb]);
            const f32x4 rb4 = *reinterpret_cast<const f32x4*>(&rm_s[rb + 4]);
            const float uj[8] = {ua[0], ua[1], ua[2], ua[3], ub[0], ub[1], ub[2], ub[3]};
            const float rj[8] = {ra[0], ra[1], ra[2], ra[3], rb4[0], rb4[1], rb4[2], rb4[3]};
            #pragma unroll
            for (int j = 0; j < 8; ++j) {
                const int rowj = rb + j;
                const float tv = uj[j] * bf2f(kb[j]) * vc;
                const bool bit = (rowj < nt) && cv && (tv == rj[j]) && (tv == cmv);
                has |= bit ? 1 : 0;
            }
        }
        has = swz16_ori(has);
        has |= __shfl_xor(has, 32, 64);
        if (lk == 0 && cv) {
            const int kk = nt * stride + mycol;
            Ot[kk] = ubd * vc;
            Oa[kk] = has ? 0.0f : 1.0f;
        }
    }
    if (tid == 0) {
        const int kk = nt * stride + nd;
        Ot[kk] = ubd * vbd;
        Oa[kk] = 0.0f;
    }

    // interior + deaths (row-panel, 16B-packed stores per 4-col group)
    {
        const float ur = u_f[myrow];
        const bool rv = (myrow < nt);
        int has = 0;
        #pragma unroll
        for (int t = 0; t < 8; ++t) {
            const int cb = 32 * t + 8 * lk;
            const f32x4 va  = *reinterpret_cast<const f32x4*>(&v_f[cb]);
            const f32x4 vb  = *reinterpret_cast<const f32x4*>(&v_f[cb + 4]);
            const f32x4 ca  = *reinterpret_cast<const f32x4*>(&cm_s[cb]);
            const f32x4 cb4 = *reinterpret_cast<const f32x4*>(&cm_s[cb + 4]);
            float tvs[8];
            float abs_[8];
            #pragma unroll
            for (int j = 0; j < 4; ++j) {
                const float tv = ur * bf2f(KA[t][j]) * va[j];
                const bool bit = rv && ((cb + j) < nd) && (tv == rm) && (tv == ca[j]);
                tvs[j] = tv; abs_[j] = bit ? 1.0f : 0.0f;
                has |= bit ? 1 : 0;
            }
            #pragma unroll
            for (int j = 0; j < 4; ++j) {
                const float tv = ur * bf2f(KA[t][4 + j]) * vb[j];
                const bool bit = rv && ((cb + 4 + j) < nd) && (tv == rm) && (tv == cb4[j]);
                tvs[4 + j] = tv; abs_[4 + j] = bit ? 1.0f : 0.0f;
                has |= bit ? 1 : 0;
            }
            if (rv) {
                float* OtR = Ot + (size_t)myrow * stride;
                float* OaR = Oa + (size_t)myrow * stride;
                #pragma unroll
                for (int g = 0; g < 2; ++g) {
                    const int c0 = cb + 4 * g;
                    if (c0 + 3 < nd) {
                        F4 ot = {tvs[4*g], tvs[4*g+1], tvs[4*g+2], tvs[4*g+3]};
                        F4 oa = {abs_[4*g], abs_[4*g+1], abs_[4*g+2], abs_[4*g+3]};
                        *reinterpret_cast<F4*>(OtR + c0) = ot;
                        *reinterpret_cast<F4*>(OaR + c0) = oa;
                    } else {
                        #pragma unroll
                        for (int j = 0; j < 4; ++j) {
                            if (c0 + j < nd) {
                                OtR[c0 + j] = tvs[4*g + j];
                                OaR[c0 + j] = abs_[4*g + j];
                            }
                        }
                    }
                }
            }
        }
        has = swz16_ori(has);
        has |= __shfl_xor(has, 32, 64);
        if (lk == 0 && rv) {
            const int kk = myrow * stride + nd;
            Ot[kk] = ur * vbd;
            Oa[kk] = has ? 0.0f : 1.0f;
        }
    }

    // zero-fill padding [length, L_FLAT)
    const int length = (nt + 1) * stride;
    for (int k = length + tid; k < L_FLAT; k += 1024) {
        Ot[k] = 0.0f;
        Oa[k] = 0.0f;
    }
}

extern "C" void kernel_launch(void* const* d_in, const int* in_sizes, int n_in,
                              void* d_out, int out_size, void* d_ws, size_t ws_size,
                              hipStream_t stream)
{
    const float* aff  = (const float*)d_in[0];
    const int*   ndet = (const int*)d_in[1];
    const int*   ntrk = (const int*)d_in[2];
    const int    Bn   = in_sizes[1];
    float* out_t = (float*)d_out;
    float* out_a = out_t + (size_t)Bn * L_FLAT;
    assoc_sinkhorn_kernel<<<dim3(Bn), dim3(1024), 0, stream>>>(aff, ndet, ntrk, out_t, out_a);
}

// Round 8
// 391.949 us; speedup vs baseline: 1.4323x; 1.0271x over previous
//
#include <hip/hip_runtime.h>

// AssociationLayer: masked Sinkhorn (100 iters) + mutual-argmax assignment.
// R13 = R12 + VALU-fat removal in the loop.
//  R12 post-mortem (270 us, best): spill gone (WRITE 202 MB), conflicts 0,
//  VALUBusy 42% / MfmaUtil 16% -> loop is VALU-issue bound on redundant
//  scalar bookkeeping: every one of 16 waves re-sums the 16 supart/svpart
//  partials (8 b128 LDS reads + 30 adds, ~40 ops/wave/iter).
//  R13: ping-pong LDS atomics for the cross-wave sums: lane 0 of each wave
//  ds_add_f32's its partial into Su/Sv accumulator; after the barrier all
//  threads read ONE float. Two-slot parity rotation, stale slot cleared by
//  tid 0 exactly one phase after its last read (barrier-ordered).
//  Plus: loop-invariant row/col validity hoisted to float masks (mul vs
//  cmp+cndmask). Su/Sv accumulation order changes by atomic scheduling ->
//  last-ulp noise, same tie-flip class as current absmax 1.0 (thr 4.92).
//  Structure unchanged: KA regs, K^T fragment-linear in LDS (KTL), 1024 thr.

#define T_MAX   256
#define L_FLAT  (257 * 257)
#define N_ITERS 100
#define LAMBDA_F 10.0f
#define EPS_F    1e-12f

#define ROR1 0x121
#define ROR2 0x122
#define ROR4 0x124
#define ROR8 0x128

typedef short bf8   __attribute__((ext_vector_type(8)));  // 8 bf16 = 4 VGPRs
typedef float f32x4 __attribute__((ext_vector_type(4)));

struct F4 { float a, b, c, d; };   // 16B payload, 4B-aligned packed store

template<int CTRL>
__device__ __forceinline__ float dpp_addf(float x) {
    int t = __builtin_amdgcn_update_dpp(0, __float_as_int(x), CTRL, 0xF, 0xF, true);
    return x + __int_as_float(t);
}
__device__ __forceinline__ float swz16_addf(float x) {
    return x + __int_as_float(__builtin_amdgcn_ds_swizzle(__float_as_int(x), 0x401F));
}
__device__ __forceinline__ float swz16_maxf(float x) {
    return fmaxf(x, __int_as_float(__builtin_amdgcn_ds_swizzle(__float_as_int(x), 0x401F)));
}
__device__ __forceinline__ int swz16_ori(int x) {
    return x | __builtin_amdgcn_ds_swizzle(x, 0x401F);
}
__device__ __forceinline__ float fast_rcp(float x) {
#if __has_builtin(__builtin_amdgcn_rcpf)
    return __builtin_amdgcn_rcpf(x);
#else
    return 1.0f / x;
#endif
}
__device__ __forceinline__ unsigned short f2bf(float x) {   // RNE f32->bf16
    unsigned u = __float_as_uint(x);
    return (unsigned short)((u + 0x7FFFu + ((u >> 16) & 1u)) >> 16);
}
__device__ __forceinline__ float bf2f(short s) {            // exact bf16->f32
    return __uint_as_float(((unsigned)(unsigned short)s) << 16);
}

__global__ __launch_bounds__(1024, 1) void assoc_sinkhorn_kernel(
    const float* __restrict__ aff,
    const int*   __restrict__ ndet,
    const int*   __restrict__ ntrk,
    float*       __restrict__ out_t,
    float*       __restrict__ out_a)
{
    const int b   = blockIdx.x;
    const int nd  = ndet[b];
    const int nt  = ntrk[b];
    const int tid = threadIdx.x;
    const int w   = tid >> 6;     // wave 0..15 -> rows/cols 16w..16w+15
    const int l   = tid & 63;
    const int lr  = l & 15;       // m/n index within 16x16 tile
    const int lk  = l >> 4;       // k-group 0..3

    // K^T fragment-linear: [w][t][lane][8 bf16] -> 16B/lane, stride-1 b128
    __shared__ __align__(16) unsigned short KTL[16 * 8 * 64 * 8];   // 128 KB
    __shared__ __align__(16) unsigned short u_bf[256];
    __shared__ __align__(16) unsigned short v_bf[256];
    __shared__ __align__(16) float u_f[256];
    __shared__ __align__(16) float v_f[256];
    __shared__ __align__(16) float SuAcc[2];   // ping-pong cross-wave sums
    __shared__ __align__(16) float SvAcc[2];
    __shared__ __align__(16) float rm_s[256];
    __shared__ __align__(16) float cm_s[256];

    const float ndf = (float)nd;
    const float ntf = (float)nt;

    // ---------------- prologue: build bf16 K fragments ----------------
    bf8 KA[8];   // row-panel (A-op): row 16w+lr, cols 32t+8lk+j
    const float* Ab = aff + (size_t)b * (T_MAX * T_MAX);

    const int myrow = 16 * w + lr;
    const int mycol = 16 * w + lr;
    unsigned short* myKTL = &KTL[(size_t)(w * 8 * 64 + l) * 8];   // + t*512

    {
        const bool rv = (myrow < nt);
        const float* rp = Ab + (size_t)myrow * T_MAX;
        #pragma unroll
        for (int t = 0; t < 8; ++t) {
            const int c0 = 32 * t + 8 * lk;
            const float4 x0 = *reinterpret_cast<const float4*>(rp + c0);
            const float4 x1 = *reinterpret_cast<const float4*>(rp + c0 + 4);
            const float e[8] = {x0.x, x0.y, x0.z, x0.w, x1.x, x1.y, x1.z, x1.w};
            bf8 kk;
            #pragma unroll
            for (int j = 0; j < 8; ++j) {
                const float val = (rv && (c0 + j) < nd) ? __expf(LAMBDA_F * e[j]) : 0.0f;
                kk[j] = (short)f2bf(val);
            }
            KA[t] = kk;
        }
    }
    {
        // col-panel (B-op): col 16w+lr, rows 32t+8lk+j -> straight to LDS
        const bool cv = (mycol < nd);
        #pragma unroll
        for (int t = 0; t < 8; ++t) {
            const int r0 = 32 * t + 8 * lk;
            bf8 kk;
            #pragma unroll
            for (int j = 0; j < 8; ++j) {
                const float x = Ab[(size_t)(r0 + j) * T_MAX + mycol];
                const float val = (cv && (r0 + j) < nt) ? __expf(LAMBDA_F * x) : 0.0f;
                kk[j] = (short)f2bf(val);
            }
            *reinterpret_cast<bf8*>(myKTL + t * 512) = kk;   // lane-linear b128
        }
    }

    if (tid < 256) v_bf[tid] = (tid < nd) ? f2bf(1.0f) : (unsigned short)0;
    if (tid == 0) {
        SuAcc[0] = 0.0f; SuAcc[1] = 0.0f;
        SvAcc[0] = ndf;  SvAcc[1] = 0.0f;   // initial Sv = nd (v=1 on valid cols)
    }
    __syncthreads();

    float vbd = 1.0f;   // v[nd]
    float ubd = 0.0f;   // u[nt]

    const int r_a0 = 16 * w + 4 * lk;   // base row of this lane's acc quad
    float u4[4] = {0.f, 0.f, 0.f, 0.f};
    float v0 = 0.0f;

    // loop-invariant validity masks (mul instead of cmp+cndmask in loop)
    float rvm[4];
    #pragma unroll
    for (int q = 0; q < 4; ++q) rvm[q] = ((r_a0 + q) < nt) ? 1.0f : 0.0f;
    const float cvm = (mycol < nd) ? 1.0f : 0.0f;

    // ---------------- Sinkhorn iterations ----------------
    for (int it = 0; it < N_ITERS; ++it) {
        const int p = it & 1;
        const float Sv = SvAcc[p];   // broadcast read; consumed in dir2 (slack)

        // ---- dir1: p = K @ v (KA regs; VF = broadcast of v) ----
        f32x4 acc = {0.0f, 0.0f, 0.0f, 0.0f};
        #pragma unroll
        for (int t = 0; t < 8; ++t) {
            const bf8 VF = *reinterpret_cast<const bf8*>(&v_bf[32 * t + 8 * lk]);
            acc = __builtin_amdgcn_mfma_f32_16x16x32_bf16(KA[t], VF, acc, 0, 0, 0);
        }

        const float vbdE = vbd + EPS_F;
        #pragma unroll
        for (int q = 0; q < 4; ++q)
            u4[q] = rvm[q] * fast_rcp(acc[q] + vbdE);

        // wave Sigma(u): sum 4 quads, fold lk groups (x16, x32), one atomic
        {
            float su = (u4[0] + u4[1]) + (u4[2] + u4[3]);
            su = swz16_addf(su);
            su += __shfl_xor(su, 32, 64);
            if (l == 0) atomicAdd(&SuAcc[p], su);
        }
        if (tid == 0) SuAcc[p ^ 1] = 0.0f;   // stale slot: last read prev iter

        // publish u as bf16; writers: lr==0 lanes (4 rows each)
        if (lr == 0) {
            const unsigned p01 = (unsigned)f2bf(u4[0]) | ((unsigned)f2bf(u4[1]) << 16);
            const unsigned p23 = (unsigned)f2bf(u4[2]) | ((unsigned)f2bf(u4[3]) << 16);
            *reinterpret_cast<uint2*>(&u_bf[r_a0]) = uint2{p01, p23};
        }
        __syncthreads();   // barrier A: u + SuAcc[p] published

        const float Su = SuAcc[p];   // one broadcast read (was 16-term tree)
        const float ubd_new = ndf * fast_rcp(Sv + vbd + EPS_F);
        const float vbd_new = ntf * fast_rcp(Su + ubd_new + EPS_F);

        // ---- dir2: q = K^T @ u (B-frags: lane-linear KTL reads) ----
        f32x4 qa = {0.0f, 0.0f, 0.0f, 0.0f};
        #pragma unroll
        for (int t = 0; t < 8; ++t) {
            const bf8 UF = *reinterpret_cast<const bf8*>(&u_bf[32 * t + 8 * lk]);
            const bf8 kb = *reinterpret_cast<const bf8*>(myKTL + t * 512);
            qa = __builtin_amdgcn_mfma_f32_16x16x32_bf16(UF, kb, qa, 0, 0, 0);
        }

        const float ubdE = ubd_new + EPS_F;
        v0 = cvm * fast_rcp(qa[0] + ubdE);

        // wave Sigma(v) over its 16 cols (varies over lr): DPP fold + atomic
        {
            float sv = v0;
            sv = dpp_addf<ROR1>(sv);
            sv = dpp_addf<ROR2>(sv);
            sv = dpp_addf<ROR4>(sv);
            sv = dpp_addf<ROR8>(sv);
            if (l == 0) atomicAdd(&SvAcc[p ^ 1], sv);
        }
        if (tid == 0) SvAcc[p] = 0.0f;   // stale slot: last read this dir1
        if (lk == 0) v_bf[mycol] = f2bf(v0);
        ubd = ubd_new;
        vbd = vbd_new;
        __syncthreads();   // barrier B: v + SvAcc[p^1] published
    }

    // ---- publish final u, v in f32 for the epilogue ----
    if (lr == 0) {
        f32x4 uf = {u4[0], u4[1], u4[2], u4[3]};
        *reinterpret_cast<f32x4*>(&u_f[r_a0]) = uf;
    }
    if (lk == 0) v_f[mycol] = v0;
    __syncthreads();

    // ================= epilogue =================
    // T = (u*k)*v with identical mul order on both panels -> bitwise-
    // consistent equality tests for mutual argmax.
    float rm;   // rowmax of this lane's row
    {
        const float ur = u_f[myrow];
        float mm = 0.0f;
        #pragma unroll
        for (int t = 0; t < 8; ++t) {
            const f32x4 va = *reinterpret_cast<const f32x4*>(&v_f[32 * t + 8 * lk]);
            const f32x4 vb = *reinterpret_cast<const f32x4*>(&v_f[32 * t + 8 * lk + 4]);
            const float vj[8] = {va[0], va[1], va[2], va[3], vb[0], vb[1], vb[2], vb[3]};
            #pragma unroll
            for (int j = 0; j < 8; ++j) {
                const float tv = ur * bf2f(KA[t][j]) * vj[j];
                mm = fmaxf(mm, tv);
            }
        }
        mm = swz16_maxf(mm);
        mm = fmaxf(mm, __shfl_xor(mm, 32, 64));
        rm = mm;
        if (lk == 0) rm_s[myrow] = mm;
    }
    float cmv;  // colmax of this lane's col
    {
        const float vc = v_f[mycol];
        float mm = 0.0f;
        #pragma unroll
        for (int t = 0; t < 8; ++t) {
            const int rb = 32 * t + 8 * lk;
            const bf8 kb = *reinterpret_cast<const bf8*>(myKTL + t * 512);
            const f32x4 ua = *reinterpret_cast<const f32x4*>(&u_f[rb]);
            const f32x4 ub = *reinterpret_cast<const f32x4*>(&u_f[rb + 4]);
            const float uj[8] = {ua[0], ua[1], ua[2], ua[3], ub[0], ub[1], ub[2], ub[3]};
            #pragma unroll
            for (int j = 0; j < 8; ++j) {
                const float tv = uj[j] * bf2f(kb[j]) * vc;
                mm = fmaxf(mm, tv);
            }
        }
        mm = swz16_maxf(mm);
        mm = fmaxf(mm, __shfl_xor(mm, 32, 64));
        cmv = mm;
        if (lk == 0) cm_s[mycol] = mm;
    }
    __syncthreads();   // rm_s / cm_s published

    float* Ot = out_t + (size_t)b * L_FLAT;
    float* Oa = out_a + (size_t)b * L_FLAT;
    const int stride = nd + 1;

    // births row (col-panel: col-has + write) + corner
    {
        const float vc = v_f[mycol];
        const bool cv = (mycol < nd);
        int has = 0;
        #pragma unroll
        for (int t = 0; t < 8; ++t) {
            const int rb = 32 * t + 8 * lk;
            const bf8 kb = *reinterpret_cast<const bf8*>(myKTL + t * 512);
            const f32x4 ua = *reinterpret_cast<const f32x4*>(&u_f[rb]);
            const f32x4 ub = *reinterpret_cast<const f32x4*>(&u_f[rb + 4]);
            const f32x4 ra = *reinterpret_cast<const f32x4*>(&rm_s[rb]);
            const f32x4 rb4 = *reinterpret_cast<const f32x4*>(&rm_s[rb + 4]);
            const float uj[8] = {ua[0], ua[1], ua[2], ua[3], ub[0], ub[1], ub[2], ub[3]};
            const float rj[8] = {ra[0], ra[1], ra[2], ra[3], rb4[0], rb4[1], rb4[2], rb4[3]};
            #pragma unroll
            for (int j = 0; j < 8; ++j) {
                const int rowj = rb + j;
                const float tv = uj[j] * bf2f(kb[j]) * vc;
                const bool bit = (rowj < nt) && cv && (tv == rj[j]) && (tv == cmv);
                has |= bit ? 1 : 0;
            }
        }
        has = swz16_ori(has);
        has |= __shfl_xor(has, 32, 64);
        if (lk == 0 && cv) {
            const int kk = nt * stride + mycol;
            Ot[kk] = ubd * vc;
            Oa[kk] = has ? 0.0f : 1.0f;
        }
    }
    if (tid == 0) {
        const int kk = nt * stride + nd;
        Ot[kk] = ubd * vbd;
        Oa[kk] = 0.0f;
    }

    // interior + deaths (row-panel, 16B-packed stores per 4-col group)
    {
        const float ur = u_f[myrow];
        const bool rv = (myrow < nt);
        int has = 0;
        #pragma unroll
        for (int t = 0; t < 8; ++t) {
            const int cb = 32 * t + 8 * lk;
            const f32x4 va  = *reinterpret_cast<const f32x4*>(&v_f[cb]);
            const f32x4 vb  = *reinterpret_cast<const f32x4*>(&v_f[cb + 4]);
            const f32x4 ca  = *reinterpret_cast<const f32x4*>(&cm_s[cb]);
            const f32x4 cb4 = *reinterpret_cast<const f32x4*>(&cm_s[cb + 4]);
            float tvs[8];
            float abs_[8];
            #pragma unroll
            for (int j = 0; j < 4; ++j) {
                const float tv = ur * bf2f(KA[t][j]) * va[j];
                const bool bit = rv && ((cb + j) < nd) && (tv == rm) && (tv == ca[j]);
                tvs[j] = tv; abs_[j] = bit ? 1.0f : 0.0f;
                has |= bit ? 1 : 0;
            }
            #pragma unroll
            for (int j = 0; j < 4; ++j) {
                const float tv = ur * bf2f(KA[t][4 + j]) * vb[j];
                const bool bit = rv && ((cb + 4 + j) < nd) && (tv == rm) && (tv == cb4[j]);
                tvs[4 + j] = tv; abs_[4 + j] = bit ? 1.0f : 0.0f;
                has |= bit ? 1 : 0;
            }
            if (rv) {
                float* OtR = Ot + (size_t)myrow * stride;
                float* OaR = Oa + (size_t)myrow * stride;
                #pragma unroll
                for (int g = 0; g < 2; ++g) {
                    const int c0 = cb + 4 * g;
                    if (c0 + 3 < nd) {
                        F4 ot = {tvs[4*g], tvs[4*g+1], tvs[4*g+2], tvs[4*g+3]};
                        F4 oa = {abs_[4*g], abs_[4*g+1], abs_[4*g+2], abs_[4*g+3]};
                        *reinterpret_cast<F4*>(OtR + c0) = ot;
                        *reinterpret_cast<F4*>(OaR + c0) = oa;
                    } else {
                        #pragma unroll
                        for (int j = 0; j < 4; ++j) {
                            if (c0 + j < nd) {
                                OtR[c0 + j] = tvs[4*g + j];
                                OaR[c0 + j] = abs_[4*g + j];
                            }
                        }
                    }
                }
            }
        }
        has = swz16_ori(has);
        has |= __shfl_xor(has, 32, 64);
        if (lk == 0 && rv) {
            const int kk = myrow * stride + nd;
            Ot[kk] = ur * vbd;
            Oa[kk] = has ? 0.0f : 1.0f;
        }
    }

    // zero-fill padding [length, L_FLAT)
    const int length = (nt + 1) * stride;
    for (int k = length + tid; k < L_FLAT; k += 1024) {
        Ot[k] = 0.0f;
        Oa[k] = 0.0f;
    }
}

extern "C" void kernel_launch(void* const* d_in, const int* in_sizes, int n_in,
                              void* d_out, int out_size, void* d_ws, size_t ws_size,
                              hipStream_t stream)
{
    const float* aff  = (const float*)d_in[0];
    const int*   ndet = (const int*)d_in[1];
    const int*   ntrk = (const int*)d_in[2];
    const int    Bn   = in_sizes[1];
    float* out_t = (float*)d_out;
    float* out_a = out_t + (size_t)Bn * L_FLAT;
    assoc_sinkhorn_kernel<<<dim3(Bn), dim3(1024), 0, stream>>>(aff, ndet, ntrk, out_t, out_a);
}